// Round 15
// baseline (45349.850 us; speedup 1.0000x reference)
//
#include <hip/hip_runtime.h>
#include <hip/hip_fp16.h>

// AlternatingForecastModel: 4096-step LSTM (B=256,H=256) with anomaly memory blend.
// v15 = v14 + DOUBLE-BUFFERED h-exchange slots (the v14 bug).
//   v14 post-mortem (absmax 0.046 = small drift, machinery worked): hslot was
//   single-buffered; the m==1 block (no out-compute) runs ~1 step ahead and
//   overwrites pslot with h_{t+2} while the partner still reads h_{t+1}.
//   With parity-indexed slots, the next same-parity write is h_{t+3}, which
//   the monotonic flag protocol provably orders after our h_{t+1} read
//   (partner needs our flag >= t+2, released a full step after that read).
//   Everything else identical to v14: 512 blocks x 256 thr (VGPR cap 256),
//   all 512KB of f16 W_hh on-chip (192 VGPR-pairs + 64KB LDS per block),
//   agent-scope release/acquire exchange, done-handshake epilogue.

#define Bb 256
#define Tt 4096
#define Ff 16
#define Hh 256
#define PV 24                    // W_hh pairs/row in VGPRs (pairs 0..23)
#define NSL 8                    // W_hh pairs/row in LDS  (pairs 24..31)
#define MEM_DECAY 0.3f
#define SMOOTH 0.1f

typedef _Float16 h2v __attribute__((ext_vector_type(2)));

__device__ __forceinline__ uint32_t pkh2(float a, float b) {
    __half2 h = __floats2half2_rn(a, b);
    return __builtin_bit_cast(uint32_t, h);
}

__device__ __forceinline__ float dot2f(uint32_t a, uint32_t b, float c) {
#if __has_builtin(__builtin_amdgcn_fdot2)
    return __builtin_amdgcn_fdot2(__builtin_bit_cast(h2v, a),
                                  __builtin_bit_cast(h2v, b), c, false);
#else
    h2v x = __builtin_bit_cast(h2v, a), y = __builtin_bit_cast(h2v, b);
    return c + (float)x[0] * (float)y[0] + (float)x[1] * (float)y[1];
#endif
}

__device__ __forceinline__ float sigm_(float x) { return 1.0f / (1.0f + __expf(-x)); }
__device__ __forceinline__ float tanh_(float x) { return 1.0f - 2.0f / (__expf(2.0f * x) + 1.0f); }

// ---------------- pre-kernel: packed anomaly bits (128 u32 words) ----------------
__global__ void __launch_bounds__(256) anom_kernel(const float* __restrict__ x,
                                                   uint32_t* __restrict__ anomw) {
    __shared__ uint32_t part[4][64];
    const int k = blockIdx.x, j = threadIdx.x;
    const int tsub = j & 63, bg = j >> 6;
    const int t = k * 64 + tsub;
    uint32_t a = 0;
    for (int b = bg * 64; b < bg * 64 + 64; ++b)
        a |= (x[((size_t)b * Tt + t) * Ff + (Ff - 1)] != 0.0f) ? 1u : 0u;
    part[bg][tsub] = a;
    __syncthreads();
    if (j < 64) {
        uint32_t any = part[0][j] | part[1][j] | part[2][j] | part[3][j];
        unsigned long long m = __ballot(any != 0);
        if (j == 0) {
            anomw[2 * k]     = (uint32_t)(m & 0xffffffffull);
            anomw[2 * k + 1] = (uint32_t)(m >> 32);
        }
    }
}

// ---------------- main kernel: 512 blocks x 256 threads ----------------
__global__ void __launch_bounds__(256, 1) lstm_kernel(
    const float* __restrict__ x,
    const float* __restrict__ W_ih, const float* __restrict__ b_ih,
    const float* __restrict__ W_hh, const float* __restrict__ b_hh,
    const float* __restrict__ W_out, const float* __restrict__ b_out,
    const uint32_t* __restrict__ anomw,
    uint32_t* hslot, uint32_t* flags,
    float* __restrict__ out)
{
    __shared__ uint4    lds_w4[2 * NSL * 256];        // 65536 B
    __shared__ float    bias_l[512];                  // 2048 B (local rows)
    __shared__ float    wout_l[256];                  // 1024 B
    __shared__ uint32_t xst[512];                     // 2048 B (64 steps x 8 pairs)
    __shared__ uint32_t hbuf[2 * 144];                // 1152 B (FULL h, stride-36 pad)
    __shared__ uint32_t abits[128];                   // 512 B
    __shared__ uint32_t w2h[64];                      // 256 B
    __shared__ float    bo_l;

    const int tid = threadIdx.x;          // 0..255
    const int bid = blockIdx.x;
    const int b   = bid >> 1;             // batch
    const int m   = bid & 1;              // half: units [128m, 128m+128)
    const int s   = tid & 3;              // k-slice (h cols [64s, 64s+64))
    const int g   = tid >> 2;             // 0..63 -> local units {2g, 2g+1}
    const int u0l = 2 * g;
    const int myul = u0l + (s & 1);       // local unit (lanes s, s+2 duplicate)
    const int gu  = 128 * m + myul;       // global unit

    // ---- VGPR W_hh: wv[r][k], r = u01*4+G, global row = G*256 + 128m + u0l + u01
    uint32_t wv[8][PV];
#pragma unroll
    for (int r = 0; r < 8; ++r) {
        const int row = ((r & 3) << 8) + 128 * m + u0l + (r >> 2);
        const float* src = W_hh + (size_t)row * Hh + 64 * s;
#pragma unroll
        for (int k = 0; k < PV; ++k) {
            const float2 w2v = *reinterpret_cast<const float2*>(src + 2 * k);
            wv[r][k] = pkh2(w2v.x, w2v.y);
        }
    }
    // ---- VGPR W_ih: slice s owns features 4s..4s+3 (2 pairs)
    uint32_t wx[8][2];
#pragma unroll
    for (int r = 0; r < 8; ++r) {
        const int row = ((r & 3) << 8) + 128 * m + u0l + (r >> 2);
        const float* src = W_ih + (size_t)row * (Ff + 1) + 4 * s;
        wx[r][0] = pkh2(src[0], src[1]);
        wx[r][1] = pkh2(src[2], src[3]);
    }
    // ---- LDS W_hh pairs 24..31: chunk c = j*2+u01, [c][tid][4dw] (proven layout)
#pragma unroll 1
    for (int c = 0; c < 2 * NSL; ++c) {
        const int j = c >> 1, u01 = c & 1;
        const int col = 64 * s + 2 * (PV + j);
        uint32_t d[4];
#pragma unroll
        for (int G = 0; G < 4; ++G) {
            const int row = (G << 8) + 128 * m + u0l + u01;
            const float2 w2v = *reinterpret_cast<const float2*>(
                W_hh + (size_t)row * Hh + col);
            d[G] = pkh2(w2v.x, w2v.y);
        }
        lds_w4[c * 256 + tid] = make_uint4(d[0], d[1], d[2], d[3]);
    }

    // ---- misc LDS init
    for (int i = tid; i < 512; i += 256)
        bias_l[i] = b_ih[((i & 3) << 8) + 128 * m + (i >> 2)] +
                    b_hh[((i & 3) << 8) + 128 * m + (i >> 2)];
    wout_l[tid] = W_out[tid];
    if (tid == 0) bo_l = b_out[0];
    if (tid < 128) abits[tid] = anomw[tid];
    for (int i = tid; i < 288; i += 256) hbuf[i] = 0u;    // h0 = 0 (both phases)
    if (tid < 50) {
        const int cc = tid / 5 + 1, j = tid % 5;
        float S = 0.f;
        for (int i = 0; i < cc; ++i) S += __expf((float)i);
        const int shift = 10 - cc;
        const int p0 = 2 * j, p1 = 2 * j + 1;
        const float v0 = (p0 >= shift) ? __expf((float)(p0 - shift)) / S : 0.f;
        const float v1 = (p1 >= shift) ? __expf((float)(p1 - shift)) / S : 0.f;
        w2h[cc * 5 + j] = pkh2(v0, v1);
    }

    float c_reg = 0.f, h_last = 0.f;
    uint32_t bufp[5];
#pragma unroll
    for (int i = 0; i < 5; ++i) bufp[i] = 0u;
    int count = 1;

    uint32_t* myflag = flags + bid;
    uint32_t* pflag  = flags + (bid ^ 1);

    __syncthreads();

    unsigned short* hs = reinterpret_cast<unsigned short*>(hbuf);

#pragma unroll 1
    for (int tc = 0; tc < Tt / 64; ++tc) {
        // stage 64 steps of x as f16 pairs (2 dwords per thread)
#pragma unroll
        for (int it = 0; it < 2; ++it) {
            const int d = tid * 2 + it;
            const int ts = tc * 64 + (d >> 3), q = d & 7;
            const float2 xv = *reinterpret_cast<const float2*>(
                &x[((size_t)b * Tt + ts) * Ff + 2 * q]);
            xst[d] = pkh2(xv.x, xv.y);
        }
        __syncthreads();

#pragma unroll 1
        for (int tt = 0; tt < 64; ++tt) {
            const int t = tc * 64 + tt;
            const uint32_t* hb = hbuf + (t & 1) * 144 + s * 36;

            float acc[8];
#pragma unroll
            for (int r = 0; r < 8; ++r) acc[r] = 0.f;

            // ---- phase A: h pairs 24..31 + LDS weight MACs
            {
                const uint4 hA1 = *reinterpret_cast<const uint4*>(hb + 24);
                const uint4 hA2 = *reinterpret_cast<const uint4*>(hb + 28);
                const uint32_t hkA[8] = {hA1.x, hA1.y, hA1.z, hA1.w,
                                         hA2.x, hA2.y, hA2.z, hA2.w};
#pragma unroll
                for (int j = 0; j < NSL; ++j) {
                    const uint32_t hk = hkA[j];
#pragma unroll
                    for (int u01 = 0; u01 < 2; ++u01) {
                        const uint4 wc = lds_w4[(j * 2 + u01) * 256 + tid];
                        acc[u01 * 4 + 0] = dot2f(wc.x, hk, acc[u01 * 4 + 0]);
                        acc[u01 * 4 + 1] = dot2f(wc.y, hk, acc[u01 * 4 + 1]);
                        acc[u01 * 4 + 2] = dot2f(wc.z, hk, acc[u01 * 4 + 2]);
                        acc[u01 * 4 + 3] = dot2f(wc.w, hk, acc[u01 * 4 + 3]);
                    }
                }
            }
            // ---- x part
            {
                const uint32_t xp0 = xst[tt * 8 + 2 * s];
                const uint32_t xp1 = xst[tt * 8 + 2 * s + 1];
#pragma unroll
                for (int r = 0; r < 8; ++r) {
                    acc[r] = dot2f(wx[r][0], xp0, acc[r]);
                    acc[r] = dot2f(wx[r][1], xp1, acc[r]);
                }
            }
            __builtin_amdgcn_sched_barrier(0);
            // ---- phase B1: h pairs 0..11
            {
                const uint4 h0 = *reinterpret_cast<const uint4*>(hb + 0);
                const uint4 h1 = *reinterpret_cast<const uint4*>(hb + 4);
                const uint4 h2 = *reinterpret_cast<const uint4*>(hb + 8);
                const uint32_t hkB[12] = {h0.x, h0.y, h0.z, h0.w,
                                          h1.x, h1.y, h1.z, h1.w,
                                          h2.x, h2.y, h2.z, h2.w};
#pragma unroll
                for (int k = 0; k < 12; ++k) {
                    const uint32_t hk = hkB[k];
#pragma unroll
                    for (int r = 0; r < 8; ++r)
                        acc[r] = dot2f(wv[r][k], hk, acc[r]);
                }
            }
            __builtin_amdgcn_sched_barrier(0);
            // ---- phase B2: h pairs 12..23
            {
                const uint4 h3 = *reinterpret_cast<const uint4*>(hb + 12);
                const uint4 h4 = *reinterpret_cast<const uint4*>(hb + 16);
                const uint4 h5 = *reinterpret_cast<const uint4*>(hb + 20);
                const uint32_t hkC[12] = {h3.x, h3.y, h3.z, h3.w,
                                          h4.x, h4.y, h4.z, h4.w,
                                          h5.x, h5.y, h5.z, h5.w};
#pragma unroll
                for (int k = 0; k < 12; ++k) {
                    const uint32_t hk = hkC[k];
#pragma unroll
                    for (int r = 0; r < 8; ++r)
                        acc[r] = dot2f(wv[r][12 + k], hk, acc[r]);
                }
            }

            // butterfly across the 4 k-slices
#pragma unroll
            for (int r = 0; r < 8; ++r) acc[r] += __shfl_xor(acc[r], 1, 64);
#pragma unroll
            for (int r = 0; r < 8; ++r) acc[r] += __shfl_xor(acc[r], 2, 64);

            const float4 bi = *reinterpret_cast<const float4*>(&bias_l[myul * 4]);
            const float g0 = ((s & 1) ? acc[4] : acc[0]) + bi.x;
            const float g1 = ((s & 1) ? acc[5] : acc[1]) + bi.y;
            const float g2 = ((s & 1) ? acc[6] : acc[2]) + bi.z;
            const float g3 = ((s & 1) ? acc[7] : acc[3]) + bi.w;

            const float ig = sigm_(g0);
            const float fg = sigm_(g1);
            const float gg = tanh_(g2);
            const float og = sigm_(g3);
            const float new_c = fg * c_reg + ig * gg;
            const float new_h = og * tanh_(new_c);

            const uint32_t an = (abits[t >> 5] >> (t & 31)) & 1u;
            if (an) {
                const uint32_t* wt = w2h + count * 5;
                float wsum = 0.f;
#pragma unroll
                for (int j = 0; j < 5; ++j) wsum = dot2f(wt[j], bufp[j], wsum);
                const float blend = wsum * (1.0f - MEM_DECAY) + new_c * MEM_DECAY;
                c_reg = c_reg * (1.0f - SMOOTH) + blend * SMOOTH;
            } else {
                c_reg = new_c;
                __half nch = __float2half_rn(new_c);
                const uint32_t nc = (uint32_t)__builtin_bit_cast(unsigned short, nch);
                bufp[0] = __builtin_amdgcn_alignbit(bufp[1], bufp[0], 16);
                bufp[1] = __builtin_amdgcn_alignbit(bufp[2], bufp[1], 16);
                bufp[2] = __builtin_amdgcn_alignbit(bufp[3], bufp[2], 16);
                bufp[3] = __builtin_amdgcn_alignbit(bufp[4], bufp[3], 16);
                bufp[4] = __builtin_amdgcn_alignbit(nc,      bufp[4], 16);
                count = min(count + 1, 10);
            }
            h_last = new_h;

            // ---- publish own half: LDS (s<2) + global pair dword (s==0),
            //      DOUBLE-BUFFERED by h-index parity (t+1)&1
            uint32_t* wrslot = hslot + ((size_t)bid << 7) + (((t + 1) & 1) << 6);
            uint32_t* rdslot = hslot + ((size_t)(bid ^ 1) << 7) + (((t + 1) & 1) << 6);
            const __half hv = __float2half_rn(new_h);
            const uint32_t ho = (uint32_t)__builtin_bit_cast(unsigned short, hv);
            const uint32_t hon = __shfl_xor(ho, 1, 64);   // unit 2g+1's value on s==0
            if (s < 2)
                hs[((t + 1) & 1) * 288 + (gu >> 6) * 72 + (gu & 63)] =
                    (unsigned short)ho;
            if (s == 0)
                __hip_atomic_store(&wrslot[g], ho | (hon << 16),
                                   __ATOMIC_RELAXED, __HIP_MEMORY_SCOPE_AGENT);
            asm volatile("s_waitcnt vmcnt(0)" ::: "memory");
            __syncthreads();                               // all h stores coherent-visible

            if (tid == 0)
                __hip_atomic_store(myflag, (uint32_t)(t + 1),
                                   __ATOMIC_RELEASE, __HIP_MEMORY_SCOPE_AGENT);
            if (tid < 64) {
                while (__hip_atomic_load(pflag, __ATOMIC_ACQUIRE,
                                         __HIP_MEMORY_SCOPE_AGENT) < (uint32_t)(t + 1))
                    __builtin_amdgcn_s_sleep(2);
                const uint32_t pd = __hip_atomic_load(&rdslot[tid], __ATOMIC_RELAXED,
                                                      __HIP_MEMORY_SCOPE_AGENT);
                const int gu0 = 128 * (1 - m) + 2 * tid;
                hbuf[((t + 1) & 1) * 144 + (gu0 >> 6) * 36 + ((gu0 & 63) >> 1)] = pd;
                if (m == 0) {
                    // out[b][t] = W_out . h_{t+1} + b_out (full h now in LDS)
                    const unsigned short* hs2 = hs + ((t + 1) & 1) * 288;
                    float ov = 0.f;
#pragma unroll
                    for (int kk = 0; kk < 4; ++kk) {
                        const unsigned short hu = hs2[kk * 72 + tid];
                        const float hvf = __half2float(__builtin_bit_cast(__half, hu));
                        ov = fmaf(wout_l[kk * 64 + tid], hvf, ov);
                    }
#pragma unroll
                    for (int mm = 1; mm < 64; mm <<= 1) ov += __shfl_xor(ov, mm, 64);
                    if (tid == 0) out[(size_t)b * Tt + t] = ov + bo_l;
                }
            }
            __syncthreads();                               // h_{t+1} complete in LDS
        }
    }

    // done-handshake: partner must finish reading our hslot before we may
    // overwrite the exchange region (it may be carved from out's final-c space)
    if (tid == 0)
        __hip_atomic_store(myflag, (uint32_t)(Tt + 1),
                           __ATOMIC_RELEASE, __HIP_MEMORY_SCOPE_AGENT);
    if (tid < 64)
        while (__hip_atomic_load(pflag, __ATOMIC_ACQUIRE,
                                 __HIP_MEMORY_SCOPE_AGENT) < (uint32_t)(Tt + 1))
            __builtin_amdgcn_s_sleep(2);
    __syncthreads();

    // final h, c (own half)
    if (s < 2) {
        out[(size_t)Bb * Tt + (size_t)b * Hh + gu] = h_last;
        out[(size_t)Bb * Tt + (size_t)Bb * Hh + (size_t)b * Hh + gu] = c_reg;
    }
}

extern "C" void kernel_launch(void* const* d_in, const int* in_sizes, int n_in,
                              void* d_out, int out_size, void* d_ws, size_t ws_size,
                              hipStream_t stream) {
    (void)in_sizes; (void)n_in; (void)out_size;
    const float* x     = (const float*)d_in[0];
    const float* W_ih  = (const float*)d_in[1];
    const float* b_ih  = (const float*)d_in[2];
    const float* W_hh  = (const float*)d_in[3];
    const float* b_hh  = (const float*)d_in[4];
    const float* W_out = (const float*)d_in[5];
    const float* b_out = (const float*)d_in[6];
    float* out = (float*)d_out;

    // scratch: [anomw 512B][hslot 512*128*4B dbuf][flags 512*4B] = 264704 B.
    // Fallback: out's final-c region (1MB, overwritten only in epilogue AFTER
    // the done-handshake) if d_ws is too small.
    const size_t NEED = 512 + (size_t)512 * 128 * 4 + 512 * 4;
    uint8_t* base = (ws_size >= NEED)
                        ? (uint8_t*)d_ws
                        : (uint8_t*)(out + (size_t)Bb * Tt + (size_t)Bb * Hh);
    uint32_t* anomw = (uint32_t*)base;
    uint32_t* hslot = (uint32_t*)(base + 512);
    uint32_t* flags = (uint32_t*)(base + 512 + (size_t)512 * 128 * 4);

    hipMemsetAsync(flags, 0, 512 * 4, stream);
    anom_kernel<<<64, 256, 0, stream>>>(x, anomw);
    lstm_kernel<<<512, 256, 0, stream>>>(x, W_ih, b_ih, W_hh, b_hh, W_out, b_out,
                                         anomw, hslot, flags, out);
}